// Round 4
// baseline (368.455 us; speedup 1.0000x reference)
//
#include <hip/hip_runtime.h>
#include <hip/hip_bf16.h>
#include <stdint.h>

typedef __bf16 v8y __attribute__((ext_vector_type(8)));
typedef _Float16 v8h __attribute__((ext_vector_type(8)));
typedef float  v4f __attribute__((ext_vector_type(4)));
typedef float  v16f __attribute__((ext_vector_type(16)));
typedef __hip_bfloat16 bf;

#define AS1 __attribute__((address_space(1)))
#define AS3 __attribute__((address_space(3)))

__device__ __forceinline__ void gload16(const bf* g, bf* l) {
  __builtin_amdgcn_global_load_lds((const AS1 uint32_t*)g, (AS3 uint32_t*)l, 16, 0, 0);
}

static constexpr int Bb = 4, Sdim = 2048, Ddim = 1024, Hn = 16, HD = 64;
static constexpr int Kd = 1024, Nd = 1024;
static constexpr int WSZ = Ddim * Ddim;
static constexpr float NEG = -1e30f;   // finite "minus infinity" — fast-math safe
static constexpr float QSCALE = 0.18033688011112042f;  // 0.125 * log2(e): exp2-domain scores

__device__ __forceinline__ void stc(bf* p, float v)    { *p = __float2bfloat16(v); }
__device__ __forceinline__ void stc(float* p, float v) { *p = v; }

__device__ __forceinline__ uint32_t pkbf(float lo, float hi_) {
  union { bf h[2]; uint32_t u; } t;
  t.h[0] = __float2bfloat16(lo);
  t.h[1] = __float2bfloat16(hi_);
  return t.u;
}

// fp32 -> fp16, 8 elems per lane (for GEMM A / Wq / Wk / Wv)
__global__ __launch_bounds__(256)
void cvt_f16(const float* __restrict__ src, uint16_t* __restrict__ dst, int n) {
  const int i = (blockIdx.x * 256 + threadIdx.x) * 8;
  if (i >= n) return;
  const float4 a = *reinterpret_cast<const float4*>(src + i);
  const float4 b = *reinterpret_cast<const float4*>(src + i + 4);
  const float x[8] = {a.x, a.y, a.z, a.w, b.x, b.y, b.z, b.w};
  union { uint16_t h[8]; uint4 u; } U;
#pragma unroll
  for (int j = 0; j < 8; ++j) U.h[j] = __builtin_bit_cast(uint16_t, (_Float16)x[j]);
  *reinterpret_cast<uint4*>(dst + i) = U.u;
}

// Weight conversions: Wq/Wk/Wv -> fp16, Wo -> bf16. wb layout: [wq wk wv wo], WSZ each.
__global__ __launch_bounds__(256)
void cvt_w(const float* __restrict__ Wq, const float* __restrict__ Wk,
           const float* __restrict__ Wv, const float* __restrict__ Wo,
           uint16_t* __restrict__ wb) {
  const int i = (blockIdx.x * 256 + threadIdx.x) * 8;
  const int z = blockIdx.y;
  const float* src = z == 0 ? Wq : (z == 1 ? Wk : (z == 2 ? Wv : Wo));
  uint16_t* dst = wb + (size_t)WSZ * z;
  const float4 a = *reinterpret_cast<const float4*>(src + i);
  const float4 b = *reinterpret_cast<const float4*>(src + i + 4);
  const float x[8] = {a.x, a.y, a.z, a.w, b.x, b.y, b.z, b.w};
  union { uint16_t h[8]; uint4 u; } U;
  if (z < 3) {
#pragma unroll
    for (int j = 0; j < 8; ++j) U.h[j] = __builtin_bit_cast(uint16_t, (_Float16)x[j]);
  } else {
#pragma unroll
    for (int j = 0; j < 8; ++j) U.h[j] = __builtin_bit_cast(uint16_t, __float2bfloat16(x[j]));
  }
  *reinterpret_cast<uint4*>(dst + i) = U.u;
}

// Additive key-mask bias, bf16: 0.0 for live keys, NEG for masked.
// Consumed by attn's mask-init MFMA (S^T row init), so no per-score VALU masking.
__global__ __launch_bounds__(256)
void maskpack(const int* __restrict__ mask, bf* __restrict__ mbias) {
  const int gid = blockIdx.x * 256 + threadIdx.x;   // over B*S = 8192
  mbias[gid] = __float2bfloat16(mask[gid] ? 0.f : NEG);
}

// C = A @ W^T + bias.  128x128 tile, BK=32, 4 waves, 4x4 grid of 16x16x32 MFMAs.
// F16: A/W are fp16 bits (single precision path, mfma_f32_16x16x32_f16).
// HEADLAYOUT: z==0 -> Q (b,h,s,hd) PRE-SCALED by QSCALE (exp2 domain); z==1 -> K;
// z==2 -> V TRANSPOSED (b,h,hd,s).
template<bool F16, bool HEADLAYOUT, typename TC>
__global__ __launch_bounds__(256)
void gemm_bt(const bf* __restrict__ A,
             const bf* __restrict__ W0, const bf* __restrict__ W1, const bf* __restrict__ W2,
             const float* __restrict__ b0, const float* __restrict__ b1, const float* __restrict__ b2,
             TC* __restrict__ C0, TC* __restrict__ C1, TC* __restrict__ C2)
{
  const int z = blockIdx.z;
  const bf* Wh = z == 0 ? W0 : (z == 1 ? W1 : W2);
  const float* bias = z == 0 ? b0 : (z == 1 ? b1 : b2);
  TC* C = z == 0 ? C0 : (z == 1 ? C1 : C2);

  constexpr int PL = 128 * 32;
  __shared__ __align__(16) bf As[PL];
  __shared__ __align__(16) bf Bs[PL];

  const int tid = threadIdx.x;
  const int w = tid >> 6, l = tid & 63;
  const int m0 = blockIdx.x * 128, n0 = blockIdx.y * 128;
  const int wm = (w & 1) * 64, wn = (w >> 1) * 64;
  const int lr = l & 15, quad = l >> 4;
  const int srow = l >> 2, sk = (l & 3) * 8;

  v4f acc[4][4] = {};

  for (int kt = 0; kt < Kd; kt += 32) {
    __syncthreads();
#pragma unroll
    for (int c = 0; c < 2; ++c) {
      const int rb = (c * 4 + w) * 16;
      const int64_t goff = (int64_t)(rb + srow) * Kd + kt + sk;
      gload16(A + (int64_t)m0 * Kd + goff, As + rb * 32);
      gload16(Wh + (int64_t)n0 * Kd + goff, Bs + rb * 32);
    }
    __syncthreads();

    v8y afh[4], bfh[4];
#pragma unroll
    for (int i = 0; i < 4; ++i) {
      const int ro = (wm + i * 16 + lr) * 32 + quad * 8;
      const int co = (wn + i * 16 + lr) * 32 + quad * 8;
      afh[i] = *reinterpret_cast<const v8y*>(As + ro);
      bfh[i] = *reinterpret_cast<const v8y*>(Bs + co);
    }
#pragma unroll
    for (int i = 0; i < 4; ++i)
#pragma unroll
      for (int j = 0; j < 4; ++j) {
        if constexpr (F16) {
          acc[i][j] = __builtin_amdgcn_mfma_f32_16x16x32_f16(
              __builtin_bit_cast(v8h, afh[i]), __builtin_bit_cast(v8h, bfh[j]),
              acc[i][j], 0, 0, 0);
        } else {
          acc[i][j] = __builtin_amdgcn_mfma_f32_16x16x32_bf16(afh[i], bfh[j], acc[i][j], 0, 0, 0);
        }
      }
  }

  // Epilogue: C/D layout col = lane&15, row = quad*4 + reg (m89-verified).
#pragma unroll
  for (int j = 0; j < 4; ++j) {
    const int gn = n0 + wn + j * 16 + lr;
    const float bv = bias[gn];
#pragma unroll
    for (int i = 0; i < 4; ++i) {
#pragma unroll
      for (int r = 0; r < 4; ++r) {
        const int gm = m0 + wm + i * 16 + quad * 4 + r;
        float v = acc[i][j][r] + bv;
        if (HEADLAYOUT) {
          const int bidx = gm >> 11, s = gm & (Sdim - 1);
          const int h = gn >> 6, hd = gn & (HD - 1);
          if (z == 0) v *= QSCALE;   // fold 1/sqrt(hd) * log2(e) into Q
          const int64_t idx = (z == 2)
            ? ((int64_t)(bidx * Hn + h) * HD + hd) * Sdim + s      // V transposed
            : (((int64_t)(bidx * Hn + h) * Sdim + s) << 6) + hd;   // Q/K natural
          stc(&C[idx], v);
        } else {
          stc(&C[(int64_t)gm * Nd + gn], v);
        }
      }
    }
  }
}

// ---------------------------------------------------------------------------
// Flash attention, 32x32 swapped-QK^T structure (m214-style), 64-key tiles.
// Scores in exp2 domain (Q pre-scaled by log2e/8). Softmax fully in-register.
// Key mask folded into the S^T accumulator INIT via one MFMA per 32-key
// subtile: A-frag = mbias[key] at k=0 (from a 4KB LDS-staged row), B-frag =
// ones at k=0. Masked scores start at -1e30 -> exp2 -> exactly 0; no per-score
// VALU masking anywhere. Defer-max (T13, THR=11 in log2 units): skip O/l
// rescale while max growth <= 11 (p bounded by 2^11, bf16-safe).
// Register discipline (round-3 lesson): no persistent per-tile state beyond
// R2's 76-VGPR baseline; all mask operands are transient.
// ---------------------------------------------------------------------------
__global__ __launch_bounds__(256)
void attn_kernel(const bf* __restrict__ qh, const bf* __restrict__ kh,
                 const bf* __restrict__ vt, const int* __restrict__ mask,
                 const bf* __restrict__ mbias, bf* __restrict__ outp)
{
  __shared__ __align__(16) bf sm[2][8192];   // [buf][ K(4096 elems) | V(4096) ]
  __shared__ __align__(16) bf mb_lds[2048];  // this batch's mbias row (4KB)

  const int tid = threadIdx.x;
  const int w = tid >> 6, l = tid & 63;
  const int lq = l & 31, hi = l >> 5;
  const int bh = blockIdx.x, b = bh >> 4;
  const int q0 = blockIdx.y * 128 + w * 32;
  const int64_t base = (int64_t)bh * (Sdim * HD);

  // stage mbias row: 2048 bf16, 256 threads x 8 elems (16B)
  *reinterpret_cast<uint4*>(mb_lds + tid * 8) =
      *reinterpret_cast<const uint4*>(mbias + b * Sdim + tid * 8);

  // Q fragments: B[q=lq][k = s*16 + hi*8 + j]
  v8y qf[4];
#pragma unroll
  for (int s = 0; s < 4; ++s)
    qf[s] = *reinterpret_cast<const v8y*>(qh + base + (int64_t)(q0 + lq) * 64 + s * 16 + hi * 8);

  const bool qmask = mask[b * Sdim + q0 + lq] != 0;

  // B-frag for the mask-init MFMA: bf16 1.0 at k=0 (lo-half lanes), else 0
  union { uint32_t u[4]; v8y v; } MB1;
  MB1.u[0] = hi ? 0u : 0x00003F80u;
  MB1.u[1] = 0; MB1.u[2] = 0; MB1.u[3] = 0;

  float m_i = NEG, l_i = 0.f;
  v16f oacc[2] = {};   // O[q=lq][d = d2*32 + (r&3)+8*(r>>2)+4*hi]

  // staging: lane's swizzled within-row offset (elems) and row-within-chunk
  const int srcperm = ((l & 7) ^ (l >> 3)) * 8;
  const int srow8 = l >> 3;

#define STAGE(bufi, ktn)                                                          \
  {                                                                               \
    bf* KB_ = sm[bufi];                                                           \
    bf* VB_ = sm[bufi] + 4096;                                                    \
    _Pragma("unroll")                                                             \
    for (int i_ = 0; i_ < 2; ++i_) {                                              \
      const int c_ = w * 2 + i_;                                                  \
      const int row_ = c_ * 8 + srow8;                                            \
      gload16(kh + base + (int64_t)((ktn) + row_) * 64 + srcperm, KB_ + c_ * 512);\
      gload16(vt + base + (int64_t)row_ * Sdim + (ktn) + srcperm, VB_ + c_ * 512);\
    }                                                                             \
  }

  STAGE(0, 0);
  asm volatile("s_waitcnt vmcnt(0)" ::: "memory");
  __syncthreads();   // also covers the mb_lds ds_writes

  for (int kt = 0; kt < Sdim; kt += 64) {
    const int buf = (kt >> 6) & 1;
    if (kt + 64 < Sdim) STAGE(buf ^ 1, kt + 64);

    const bf* KB = sm[buf];
    const bf* VB = sm[buf] + 4096;

    // ---- S^T init = key-mask bias (one MFMA per 32-key subtile) ----
    // A-frag: lane row = key n*32+lq, elem k=0 = mbias[key] (u16 zext: hi
    // half = bf16 0). hi-half lanes' A irrelevant (their B is 0).
    union { uint32_t u[4]; v8y v; } MA0, MA1;
    MA0.u[0] = (uint32_t)*reinterpret_cast<const uint16_t*>(mb_lds + kt + lq);
    MA0.u[1] = 0; MA0.u[2] = 0; MA0.u[3] = 0;
    MA1.u[0] = (uint32_t)*reinterpret_cast<const uint16_t*>(mb_lds + kt + 32 + lq);
    MA1.u[1] = 0; MA1.u[2] = 0; MA1.u[3] = 0;
    const v16f zz = {};
    v16f sacc[2];
    sacc[0] = __builtin_amdgcn_mfma_f32_32x32x16_bf16(MA0.v, MB1.v, zz, 0, 0, 0);
    sacc[1] = __builtin_amdgcn_mfma_f32_32x32x16_bf16(MA1.v, MB1.v, zz, 0, 0, 0);

    // ---- S^T += K Q^T : two 32-key subtiles, 4 hd-steps each ----
    __builtin_amdgcn_s_setprio(1);
#pragma unroll
    for (int n = 0; n < 2; ++n) {
      const int row = n * 32 + lq;
      const int swz = (row & 7);
#pragma unroll
      for (int s = 0; s < 4; ++s) {
        const int colE = ((2 * s + hi) ^ swz) * 8;
        v8y kf = *reinterpret_cast<const v8y*>(KB + row * 64 + colE);
        sacc[n] = __builtin_amdgcn_mfma_f32_32x32x16_bf16(kf, qf[s], sacc[n], 0, 0, 0);
      }
    }
    __builtin_amdgcn_s_setprio(0);

    // ---- online softmax (exp2 domain), defer-max ----
    float mx = NEG;
#pragma unroll
    for (int n = 0; n < 2; ++n)
#pragma unroll
      for (int r = 0; r < 16; r += 2)
        mx = fmaxf(mx, fmaxf(sacc[n][r], sacc[n][r + 1]));   // v_max3-fusible
    mx = fmaxf(mx, __shfl_xor(mx, 32));

    if (!__all(mx - m_i <= 11.0f)) {
      const float mn = fmaxf(m_i, mx);
      const float alpha = exp2f(m_i - mn);
      m_i = mn;
      l_i *= alpha;
#pragma unroll
      for (int d2 = 0; d2 < 2; ++d2)
#pragma unroll
        for (int r = 0; r < 16; ++r) oacc[d2][r] *= alpha;
    }

    float sum = 0.f;
#pragma unroll
    for (int n = 0; n < 2; ++n)
#pragma unroll
      for (int r = 0; r < 16; ++r) {
        const float p = exp2f(sacc[n][r] - m_i);
        sacc[n][r] = p;
        sum += p;
      }
    sum += __shfl_xor(sum, 32);
    l_i += sum;

    // ---- pack P quads: pq[a] = keys 8a+4hi+{0..3} (bf16 pairs) ----
    uint32_t pq[8][2];
#pragma unroll
    for (int n = 0; n < 2; ++n)
#pragma unroll
      for (int g = 0; g < 4; ++g) {
        pq[n * 4 + g][0] = pkbf(sacc[n][g * 4 + 0], sacc[n][g * 4 + 1]);
        pq[n * 4 + g][1] = pkbf(sacc[n][g * 4 + 2], sacc[n][g * 4 + 3]);
      }

    // ---- PV: O^T += V^T P, k-steps of 16 keys; quad exchange with lane^32 ----
#pragma unroll
    for (int ks = 0; ks < 4; ++ks) {
      const uint32_t own0 = hi ? pq[2 * ks + 1][0] : pq[2 * ks][0];
      const uint32_t own1 = hi ? pq[2 * ks + 1][1] : pq[2 * ks][1];
      const uint32_t snd0 = hi ? pq[2 * ks][0] : pq[2 * ks + 1][0];
      const uint32_t snd1 = hi ? pq[2 * ks][1] : pq[2 * ks + 1][1];
      const uint32_t rc0 = (uint32_t)__shfl_xor((int)snd0, 32);
      const uint32_t rc1 = (uint32_t)__shfl_xor((int)snd1, 32);
      union { uint32_t u[4]; v8y v; } pf;
      pf.u[0] = hi ? rc0 : own0;
      pf.u[1] = hi ? rc1 : own1;
      pf.u[2] = hi ? own0 : rc0;
      pf.u[3] = hi ? own1 : rc1;
      __builtin_amdgcn_s_setprio(1);
#pragma unroll
      for (int d2 = 0; d2 < 2; ++d2) {
        const int row = d2 * 32 + lq;
        const int colE = ((2 * ks + hi) ^ (row & 7)) * 8;
        v8y vf = *reinterpret_cast<const v8y*>(VB + row * 64 + colE);
        oacc[d2] = __builtin_amdgcn_mfma_f32_32x32x16_bf16(vf, pf.v, oacc[d2], 0, 0, 0);
      }
      __builtin_amdgcn_s_setprio(0);
    }

    asm volatile("s_waitcnt vmcnt(0)" ::: "memory");
    __syncthreads();
  }
#undef STAGE

  // ---- epilogue: O[q][d] / l, masked q rows -> 0; pack 4 bf16 per store ----
  const float inv = qmask ? 1.f / l_i : 0.f;
  bf* orow = outp + ((int64_t)b * Sdim + q0 + lq) * Ddim + (bh & 15) * 64;
#pragma unroll
  for (int d2 = 0; d2 < 2; ++d2)
#pragma unroll
    for (int g = 0; g < 4; ++g) {
      union { bf h[4]; uint2 u; } pk;
#pragma unroll
      for (int c = 0; c < 4; ++c) pk.h[c] = __float2bfloat16(oacc[d2][g * 4 + c] * inv);
      *reinterpret_cast<uint2*>(orow + d2 * 32 + 8 * g + 4 * hi) = pk.u;
    }
}

extern "C" void kernel_launch(void* const* d_in, const int* in_sizes, int n_in,
                              void* d_out, int out_size, void* d_ws, size_t ws_size,
                              hipStream_t stream) {
  (void)in_sizes; (void)n_in; (void)out_size; (void)ws_size;
  const float* q    = (const float*)d_in[0];
  const int*   mask = (const int*)d_in[1];   // int32 0/1 — verified round 7
  const float* Wq = (const float*)d_in[2];
  const float* bq = (const float*)d_in[3];
  const float* Wk = (const float*)d_in[4];
  const float* bk = (const float*)d_in[5];
  const float* Wv = (const float*)d_in[6];
  const float* bv = (const float*)d_in[7];
  const float* Wo = (const float*)d_in[8];
  const float* bo = (const float*)d_in[9];
  float* out = (float*)d_out;                // fp32 output — verified round 7
  bf* ws  = (bf*)d_ws;

  constexpr int SZ = Bb * Sdim * Ddim;   // 8,388,608

  bf* qc  = ws;                    // A (fp16 bits); reused as attn output `ao` later
  bf* qhp = ws + (size_t)SZ;
  bf* khp = ws + 2 * (size_t)SZ;
  bf* vtp = ws + 3 * (size_t)SZ;   // V in (b,h,hd,s)
  bf* wb  = ws + 4 * (size_t)SZ;   // [wq wk wv (fp16), wo (bf16)], WSZ each
  bf* wq = wb;
  bf* wk = wb + WSZ;
  bf* wv = wb + 2 * (size_t)WSZ;
  bf* wo = wb + 3 * (size_t)WSZ;
  bf* mbias = wb + 4 * (size_t)WSZ;   // B*S bf16 = 16 KB
  bf* ao = qc;   // safe: QKV GEMM consumed qc before attn writes ao

  cvt_f16<<<dim3(SZ / 2048), dim3(256), 0, stream>>>(q, (uint16_t*)qc, SZ);
  cvt_w<<<dim3(WSZ / 2048, 4), dim3(256), 0, stream>>>(Wq, Wk, Wv, Wo, (uint16_t*)wb);
  maskpack<<<dim3(32), dim3(256), 0, stream>>>(mask, mbias);

  // Fused QKV projections (fp16 single) -> Q scaled (b,h,s,hd), K (b,h,s,hd), V^T (b,h,hd,s)
  gemm_bt<true, true, bf><<<dim3(64, 8, 3), dim3(256), 0, stream>>>(
      qc, wq, wk, wv, bq, bk, bv, qhp, khp, vtp);

  // Attention -> (b,s,d) bf16
  attn_kernel<<<dim3(Bb * Hn, Sdim / 128), dim3(256), 0, stream>>>(qhp, khp, vtp, mask, mbias, ao);

  // Output projection (single bf16) -> d_out fp32
  gemm_bt<false, false, float><<<dim3(64, 8, 1), dim3(256), 0, stream>>>(
      ao, wo, wo, wo, bo, bo, bo, out, out, out);
}

// Round 5
// 348.404 us; speedup vs baseline: 1.0575x; 1.0575x over previous
//
#include <hip/hip_runtime.h>
#include <hip/hip_bf16.h>
#include <stdint.h>

typedef __bf16 v8y __attribute__((ext_vector_type(8)));
typedef _Float16 v8h __attribute__((ext_vector_type(8)));
typedef float  v4f __attribute__((ext_vector_type(4)));
typedef float  v16f __attribute__((ext_vector_type(16)));
typedef unsigned u32x2 __attribute__((ext_vector_type(2)));
typedef __hip_bfloat16 bf;

#define AS1 __attribute__((address_space(1)))
#define AS3 __attribute__((address_space(3)))

__device__ __forceinline__ void gload16(const bf* g, bf* l) {
  __builtin_amdgcn_global_load_lds((const AS1 uint32_t*)g, (AS3 uint32_t*)l, 16, 0, 0);
}

static constexpr int Bb = 4, Sdim = 2048, Ddim = 1024, Hn = 16, HD = 64;
static constexpr int Kd = 1024, Nd = 1024;
static constexpr int WSZ = Ddim * Ddim;
static constexpr float NEG = -1e30f;   // finite "minus infinity" — fast-math safe

__device__ __forceinline__ void stc(bf* p, float v)    { *p = __float2bfloat16(v); }
__device__ __forceinline__ void stc(float* p, float v) { *p = v; }

__device__ __forceinline__ uint32_t pkbf(float lo, float hi_) {
  union { bf h[2]; uint32_t u; } t;
  t.h[0] = __float2bfloat16(lo);
  t.h[1] = __float2bfloat16(hi_);
  return t.u;
}

// v_permlane32_swap_b32: a'[i+32]=b[i]; b'[i]=a[i+32] (i<32); other halves keep.
__device__ __forceinline__ void plswap(uint32_t& a, uint32_t& b) {
  u32x2 r = __builtin_amdgcn_permlane32_swap(a, b, false, false);
  a = r.x; b = r.y;
}

// value of x held by the partner half-wave lane (lane ^ 32); pure VALU, no LDS.
__device__ __forceinline__ float xhalf(float x, int hi) {
  uint32_t a = __builtin_bit_cast(uint32_t, x), b = a;
  plswap(a, b);
  return __builtin_bit_cast(float, hi ? a : b);
}

// fp32 -> fp16, 8 elems per lane (for GEMM A / Wq / Wk / Wv)
__global__ __launch_bounds__(256)
void cvt_f16(const float* __restrict__ src, uint16_t* __restrict__ dst, int n) {
  const int i = (blockIdx.x * 256 + threadIdx.x) * 8;
  if (i >= n) return;
  const float4 a = *reinterpret_cast<const float4*>(src + i);
  const float4 b = *reinterpret_cast<const float4*>(src + i + 4);
  const float x[8] = {a.x, a.y, a.z, a.w, b.x, b.y, b.z, b.w};
  union { uint16_t h[8]; uint4 u; } U;
#pragma unroll
  for (int j = 0; j < 8; ++j) U.h[j] = __builtin_bit_cast(uint16_t, (_Float16)x[j]);
  *reinterpret_cast<uint4*>(dst + i) = U.u;
}

// Weight conversions: Wq/Wk/Wv -> fp16, Wo -> bf16. wb layout: [wq wk wv wo], WSZ each.
__global__ __launch_bounds__(256)
void cvt_w(const float* __restrict__ Wq, const float* __restrict__ Wk,
           const float* __restrict__ Wv, const float* __restrict__ Wo,
           uint16_t* __restrict__ wb) {
  const int i = (blockIdx.x * 256 + threadIdx.x) * 8;
  const int z = blockIdx.y;
  const float* src = z == 0 ? Wq : (z == 1 ? Wk : (z == 2 ? Wv : Wo));
  uint16_t* dst = wb + (size_t)WSZ * z;
  const float4 a = *reinterpret_cast<const float4*>(src + i);
  const float4 b = *reinterpret_cast<const float4*>(src + i + 4);
  const float x[8] = {a.x, a.y, a.z, a.w, b.x, b.y, b.z, b.w};
  union { uint16_t h[8]; uint4 u; } U;
  if (z < 3) {
#pragma unroll
    for (int j = 0; j < 8; ++j) U.h[j] = __builtin_bit_cast(uint16_t, (_Float16)x[j]);
  } else {
#pragma unroll
    for (int j = 0; j < 8; ++j) U.h[j] = __builtin_bit_cast(uint16_t, __float2bfloat16(x[j]));
  }
  *reinterpret_cast<uint4*>(dst + i) = U.u;
}

// Pack key mask into a bitmask: mp[b*32 + s/64] bit i = mask[b][s64*64+i]
__global__ __launch_bounds__(256)
void maskpack(const int* __restrict__ mask, uint64_t* __restrict__ mp) {
  const int gid = blockIdx.x * 256 + threadIdx.x;   // over B*S = 8192
  const uint64_t bal = __ballot(mask[gid] != 0);
  if ((threadIdx.x & 63) == 0) mp[gid >> 6] = bal;
}

// C = A @ W^T + bias.  128x128 tile, BK=32, 4 waves, 4x4 grid of 16x16x32 MFMAs.
// F16: A/W are fp16 bits (single precision path, mfma_f32_16x16x32_f16).
// HEADLAYOUT: z==0 -> Q (b,h,s,hd) PRE-SCALED by 0.125; z==1 -> K (b,h,s,hd);
// z==2 -> V TRANSPOSED (b,h,hd,s).
template<bool F16, bool HEADLAYOUT, typename TC>
__global__ __launch_bounds__(256)
void gemm_bt(const bf* __restrict__ A,
             const bf* __restrict__ W0, const bf* __restrict__ W1, const bf* __restrict__ W2,
             const float* __restrict__ b0, const float* __restrict__ b1, const float* __restrict__ b2,
             TC* __restrict__ C0, TC* __restrict__ C1, TC* __restrict__ C2)
{
  const int z = blockIdx.z;
  const bf* Wh = z == 0 ? W0 : (z == 1 ? W1 : W2);
  const float* bias = z == 0 ? b0 : (z == 1 ? b1 : b2);
  TC* C = z == 0 ? C0 : (z == 1 ? C1 : C2);

  constexpr int PL = 128 * 32;
  __shared__ __align__(16) bf As[PL];
  __shared__ __align__(16) bf Bs[PL];

  const int tid = threadIdx.x;
  const int w = tid >> 6, l = tid & 63;
  const int m0 = blockIdx.x * 128, n0 = blockIdx.y * 128;
  const int wm = (w & 1) * 64, wn = (w >> 1) * 64;
  const int lr = l & 15, quad = l >> 4;
  const int srow = l >> 2, sk = (l & 3) * 8;

  v4f acc[4][4] = {};

  for (int kt = 0; kt < Kd; kt += 32) {
    __syncthreads();
#pragma unroll
    for (int c = 0; c < 2; ++c) {
      const int rb = (c * 4 + w) * 16;
      const int64_t goff = (int64_t)(rb + srow) * Kd + kt + sk;
      gload16(A + (int64_t)m0 * Kd + goff, As + rb * 32);
      gload16(Wh + (int64_t)n0 * Kd + goff, Bs + rb * 32);
    }
    __syncthreads();

    v8y afh[4], bfh[4];
#pragma unroll
    for (int i = 0; i < 4; ++i) {
      const int ro = (wm + i * 16 + lr) * 32 + quad * 8;
      const int co = (wn + i * 16 + lr) * 32 + quad * 8;
      afh[i] = *reinterpret_cast<const v8y*>(As + ro);
      bfh[i] = *reinterpret_cast<const v8y*>(Bs + co);
    }
#pragma unroll
    for (int i = 0; i < 4; ++i)
#pragma unroll
      for (int j = 0; j < 4; ++j) {
        if constexpr (F16) {
          acc[i][j] = __builtin_amdgcn_mfma_f32_16x16x32_f16(
              __builtin_bit_cast(v8h, afh[i]), __builtin_bit_cast(v8h, bfh[j]),
              acc[i][j], 0, 0, 0);
        } else {
          acc[i][j] = __builtin_amdgcn_mfma_f32_16x16x32_bf16(afh[i], bfh[j], acc[i][j], 0, 0, 0);
        }
      }
  }

  // Epilogue: C/D layout col = lane&15, row = quad*4 + reg (m89-verified).
#pragma unroll
  for (int j = 0; j < 4; ++j) {
    const int gn = n0 + wn + j * 16 + lr;
    const float bv = bias[gn];
#pragma unroll
    for (int i = 0; i < 4; ++i) {
#pragma unroll
      for (int r = 0; r < 4; ++r) {
        const int gm = m0 + wm + i * 16 + quad * 4 + r;
        float v = acc[i][j][r] + bv;
        if (HEADLAYOUT) {
          const int bidx = gm >> 11, s = gm & (Sdim - 1);
          const int h = gn >> 6, hd = gn & (HD - 1);
          if (z == 0) v *= 0.125f;   // fold 1/sqrt(hd) into Q
          const int64_t idx = (z == 2)
            ? ((int64_t)(bidx * Hn + h) * HD + hd) * Sdim + s      // V transposed
            : (((int64_t)(bidx * Hn + h) * Sdim + s) << 6) + hd;   // Q/K natural
          stc(&C[idx], v);
        } else {
          stc(&C[(int64_t)gm * Nd + gn], v);
        }
      }
    }
  }
}

// ---------------------------------------------------------------------------
// Flash attention, 32x32 swapped-QK^T structure (m214-style), 64-key tiles.
// qh/kh in (b,h,s,hd); vt in (b,h,hd,s). 4 waves x 32 q-rows = 128 q/block.
// S^T = mfma(K,Q): lane owns q = lane&31, keys (r&3)+8*(r>>2)+4*hi per subtile.
// Softmax fully in-register (scalar per lane). ALL cross-lane traffic via
// v_permlane32_swap (no ds_bpermute): the pairwise swap of (pq[2ks],pq[2ks+1])
// yields exactly the PV B-fragment words for both half-waves, zero selects.
// Reductions (max/sum) as 4 independent chains + merge (depth ~10, not 32).
// K/V staged via global_load_lds: linear LDS dest + pre-swizzled source,
// XOR-swizzled reads. Double-buffered; one vmcnt(0)+barrier per tile.
// Register discipline (R3/R4 lesson): no per-tile persistent state; nothing
// added in front of the QK^T or PV MFMA chains.
// ---------------------------------------------------------------------------
__global__ __launch_bounds__(256)
void attn_kernel(const bf* __restrict__ qh, const bf* __restrict__ kh,
                 const bf* __restrict__ vt, const int* __restrict__ mask,
                 const uint64_t* __restrict__ mp, bf* __restrict__ outp)
{
  __shared__ __align__(16) bf sm[2][8192];   // [buf][ K(4096 elems) | V(4096) ]

  const int tid = threadIdx.x;
  const int w = tid >> 6, l = tid & 63;
  const int lq = l & 31, hi = l >> 5;
  const int bh = blockIdx.x, b = bh >> 4;
  const int q0 = blockIdx.y * 128 + w * 32;
  const int64_t base = (int64_t)bh * (Sdim * HD);

  // Q fragments: B[q=lq][k = s*16 + hi*8 + j]
  v8y qf[4];
#pragma unroll
  for (int s = 0; s < 4; ++s)
    qf[s] = *reinterpret_cast<const v8y*>(qh + base + (int64_t)(q0 + lq) * 64 + s * 16 + hi * 8);

  const bool qmask = mask[b * Sdim + q0 + lq] != 0;

  float m_i = NEG, l_i = 0.f;
  v16f oacc[2] = {};   // O[q=lq][d = d2*32 + (r&3)+8*(r>>2)+4*hi]

  // staging: lane's swizzled within-row offset (elems) and row-within-chunk
  const int srcperm = ((l & 7) ^ (l >> 3)) * 8;
  const int srow8 = l >> 3;

#define STAGE(bufi, ktn)                                                          \
  {                                                                               \
    bf* KB_ = sm[bufi];                                                           \
    bf* VB_ = sm[bufi] + 4096;                                                    \
    _Pragma("unroll")                                                             \
    for (int i_ = 0; i_ < 2; ++i_) {                                              \
      const int c_ = w * 2 + i_;                                                  \
      const int row_ = c_ * 8 + srow8;                                            \
      gload16(kh + base + (int64_t)((ktn) + row_) * 64 + srcperm, KB_ + c_ * 512);\
      gload16(vt + base + (int64_t)row_ * Sdim + (ktn) + srcperm, VB_ + c_ * 512);\
    }                                                                             \
  }

  STAGE(0, 0);
  asm volatile("s_waitcnt vmcnt(0)" ::: "memory");
  __syncthreads();

  for (int kt = 0; kt < Sdim; kt += 64) {
    const int buf = (kt >> 6) & 1;
    if (kt + 64 < Sdim) STAGE(buf ^ 1, kt + 64);

    const bf* KB = sm[buf];
    const bf* VB = sm[buf] + 4096;

    // ---- S^T = K Q^T : two 32-key subtiles, 4 hd-steps each ----
    v16f sacc[2] = {};
    __builtin_amdgcn_s_setprio(1);
#pragma unroll
    for (int n = 0; n < 2; ++n) {
      const int row = n * 32 + lq;
      const int swz = (row & 7);
#pragma unroll
      for (int s = 0; s < 4; ++s) {
        const int colE = ((2 * s + hi) ^ swz) * 8;
        v8y kf = *reinterpret_cast<const v8y*>(KB + row * 64 + colE);
        sacc[n] = __builtin_amdgcn_mfma_f32_32x32x16_bf16(kf, qf[s], sacc[n], 0, 0, 0);
      }
    }
    __builtin_amdgcn_s_setprio(0);

    // ---- key mask (additive, from bitmask; one scalar u64 per tile) ----
    const uint64_t km64 = mp[b * 32 + (kt >> 6)];
    const uint32_t km0 = (uint32_t)km64 >> (4 * hi);
    const uint32_t km1 = (uint32_t)(km64 >> 32) >> (4 * hi);
#pragma unroll
    for (int r = 0; r < 16; ++r) {
      const uint32_t bit = 1u << ((r & 3) + 8 * (r >> 2));
      sacc[0][r] = (km0 & bit) ? sacc[0][r] : NEG;
      sacc[1][r] = (km1 & bit) ? sacc[1][r] : NEG;
    }

    // ---- online softmax: 4-chain max tree + one permlane hop ----
    float mxc[4] = {NEG, NEG, NEG, NEG};
#pragma unroll
    for (int n = 0; n < 2; ++n)
#pragma unroll
      for (int r = 0; r < 16; r += 4) {
#pragma unroll
        for (int c = 0; c < 4; ++c) mxc[c] = fmaxf(mxc[c], sacc[n][r + c]);
      }
    float mx = fmaxf(fmaxf(mxc[0], mxc[1]), fmaxf(mxc[2], mxc[3]));
    mx = fmaxf(mx, xhalf(mx, hi));
    const float mn = fmaxf(m_i, mx);
    const float alpha = __expf(m_i - mn);
    m_i = mn;

#pragma unroll
    for (int n = 0; n < 2; ++n)
#pragma unroll
      for (int r = 0; r < 16; ++r) sacc[n][r] = __expf(sacc[n][r] - mn);

    float smc[4] = {0.f, 0.f, 0.f, 0.f};
#pragma unroll
    for (int n = 0; n < 2; ++n)
#pragma unroll
      for (int r = 0; r < 16; r += 4) {
#pragma unroll
        for (int c = 0; c < 4; ++c) smc[c] += sacc[n][r + c];
      }
    float sum = (smc[0] + smc[1]) + (smc[2] + smc[3]);
    sum += xhalf(sum, hi);
    l_i = l_i * alpha + sum;
#pragma unroll
    for (int d2 = 0; d2 < 2; ++d2)
#pragma unroll
      for (int r = 0; r < 16; ++r) oacc[d2][r] *= alpha;

    // ---- pack P quads: pq[a] = keys 8a+4hi+{0..3} (bf16 pairs) ----
    uint32_t pq[8][2];
#pragma unroll
    for (int n = 0; n < 2; ++n)
#pragma unroll
      for (int g = 0; g < 4; ++g) {
        pq[n * 4 + g][0] = pkbf(sacc[n][g * 4 + 0], sacc[n][g * 4 + 1]);
        pq[n * 4 + g][1] = pkbf(sacc[n][g * 4 + 2], sacc[n][g * 4 + 3]);
      }

    // ---- half-wave exchange via permlane32_swap: after swap, for ALL lanes
    // pq[2ks] = B-frag words j0..3 and pq[2ks+1] = j4..7 (derivation in header)
#pragma unroll
    for (int ks = 0; ks < 4; ++ks) {
      plswap(pq[2 * ks][0], pq[2 * ks + 1][0]);
      plswap(pq[2 * ks][1], pq[2 * ks + 1][1]);
    }

    // ---- PV: O^T += V^T P, k-steps of 16 keys ----
#pragma unroll
    for (int ks = 0; ks < 4; ++ks) {
      union { uint32_t u[4]; v8y v; } pf;
      pf.u[0] = pq[2 * ks][0];
      pf.u[1] = pq[2 * ks][1];
      pf.u[2] = pq[2 * ks + 1][0];
      pf.u[3] = pq[2 * ks + 1][1];
      __builtin_amdgcn_s_setprio(1);
#pragma unroll
      for (int d2 = 0; d2 < 2; ++d2) {
        const int row = d2 * 32 + lq;
        const int colE = ((2 * ks + hi) ^ (row & 7)) * 8;
        v8y vf = *reinterpret_cast<const v8y*>(VB + row * 64 + colE);
        oacc[d2] = __builtin_amdgcn_mfma_f32_32x32x16_bf16(vf, pf.v, oacc[d2], 0, 0, 0);
      }
      __builtin_amdgcn_s_setprio(0);
    }

    asm volatile("s_waitcnt vmcnt(0)" ::: "memory");
    __syncthreads();
  }
#undef STAGE

  // ---- epilogue: O[q][d] / l_i, masked q rows -> 0; pack 4 bf16 per store ----
  const float inv = qmask ? 1.f / l_i : 0.f;
  bf* orow = outp + ((int64_t)b * Sdim + q0 + lq) * Ddim + (bh & 15) * 64;
#pragma unroll
  for (int d2 = 0; d2 < 2; ++d2)
#pragma unroll
    for (int g = 0; g < 4; ++g) {
      union { bf h[4]; uint2 u; } pk;
#pragma unroll
      for (int c = 0; c < 4; ++c) pk.h[c] = __float2bfloat16(oacc[d2][g * 4 + c] * inv);
      *reinterpret_cast<uint2*>(orow + d2 * 32 + 8 * g + 4 * hi) = pk.u;
    }
}

extern "C" void kernel_launch(void* const* d_in, const int* in_sizes, int n_in,
                              void* d_out, int out_size, void* d_ws, size_t ws_size,
                              hipStream_t stream) {
  (void)in_sizes; (void)n_in; (void)out_size; (void)ws_size;
  const float* q    = (const float*)d_in[0];
  const int*   mask = (const int*)d_in[1];   // int32 0/1 — verified round 7
  const float* Wq = (const float*)d_in[2];
  const float* bq = (const float*)d_in[3];
  const float* Wk = (const float*)d_in[4];
  const float* bk = (const float*)d_in[5];
  const float* Wv = (const float*)d_in[6];
  const float* bv = (const float*)d_in[7];
  const float* Wo = (const float*)d_in[8];
  const float* bo = (const float*)d_in[9];
  float* out = (float*)d_out;                // fp32 output — verified round 7
  bf* ws  = (bf*)d_ws;

  constexpr int SZ = Bb * Sdim * Ddim;   // 8,388,608

  bf* qc  = ws;                    // A (fp16 bits); reused as attn output `ao` later
  bf* qhp = ws + (size_t)SZ;
  bf* khp = ws + 2 * (size_t)SZ;
  bf* vtp = ws + 3 * (size_t)SZ;   // V in (b,h,hd,s)
  bf* wb  = ws + 4 * (size_t)SZ;   // [wq wk wv (fp16), wo (bf16)], WSZ each
  bf* wq = wb;
  bf* wk = wb + WSZ;
  bf* wv = wb + 2 * (size_t)WSZ;
  bf* wo = wb + 3 * (size_t)WSZ;
  uint64_t* mpk = (uint64_t*)(wb + 4 * (size_t)WSZ);   // 512 u64
  bf* ao = qc;   // safe: QKV GEMM consumed qc before attn writes ao

  cvt_f16<<<dim3(SZ / 2048), dim3(256), 0, stream>>>(q, (uint16_t*)qc, SZ);
  cvt_w<<<dim3(WSZ / 2048, 4), dim3(256), 0, stream>>>(Wq, Wk, Wv, Wo, (uint16_t*)wb);
  maskpack<<<dim3(32), dim3(256), 0, stream>>>(mask, mpk);

  // Fused QKV projections (fp16 single) -> Q scaled (b,h,s,hd), K (b,h,s,hd), V^T (b,h,hd,s)
  gemm_bt<true, true, bf><<<dim3(64, 8, 3), dim3(256), 0, stream>>>(
      qc, wq, wk, wv, bq, bk, bv, qhp, khp, vtp);

  // Attention -> (b,s,d) bf16
  attn_kernel<<<dim3(Bb * Hn, Sdim / 128), dim3(256), 0, stream>>>(qhp, khp, vtp, mask, mpk, ao);

  // Output projection (single bf16) -> d_out fp32
  gemm_bt<false, false, float><<<dim3(64, 8, 1), dim3(256), 0, stream>>>(
      ao, wo, wo, wo, bo, bo, bo, out, out, out);
}